// Round 1
// baseline (778.932 us; speedup 1.0000x reference)
//
#include <hip/hip_runtime.h>
#include <math.h>

#define BB 256
#define TT 512
#define KK 128

// padded LDS index: +4 floats per 32 to break the 128B==32-bank wrap
#define AIDX(i) ((i) + (((i) >> 5) << 2))

__global__ __launch_bounds__(512, 1) void crf_forward(
    const float* __restrict__ logits,     // [B,T,K]
    const int* __restrict__ labels,       // [B,T]
    const int* __restrict__ seq_lens,     // [B]
    const float* __restrict__ trans,      // [K,K]
    float* __restrict__ pred_out,         // [B,T] as float (d_out+1)
    float* __restrict__ negll,            // [B] in ws
    unsigned char* __restrict__ bp)       // [B,T,K] backpointers in ws
{
  const int b = blockIdx.x;
  const int tid = threadIdx.x;
  const int j = tid >> 2;      // state column owned (0..127)
  const int sub = tid & 3;     // i-subrange (4 threads per column)
  const int i0 = sub * 32;
  const int L = seq_lens[b];

  __shared__ float av[144];          // viterbi alpha (padded)
  __shared__ float ev[144];          // scaled forward probs (padded)
  __shared__ float emit_s[KK];
  __shared__ float wmax[8];          // per-wave maxes of ev (delayed renorm)
  __shared__ unsigned char tags[TT];
  __shared__ float rv[8]; __shared__ int ri[8];
  __shared__ float rs[8]; __shared__ float rsc[8];
  __shared__ int last_s;

  // trans column j, rows [i0, i0+32): raw for viterbi, exp() for log-norm
  float tv[32], tw[32];
#pragma unroll
  for (int ii = 0; ii < 32; ++ii) {
    float tr = trans[(i0 + ii) * KK + j];
    tv[ii] = tr;
    tw[ii] = __expf(tr);
  }

  if (tid < KK) {
    float l0 = logits[(b * TT) * KK + tid];
    av[AIDX(tid)] = l0;
    ev[AIDX(tid)] = __expf(l0);   // alpha_l0 = logits[:,0]; linear domain, Cln=0
  }
  if (tid < 8) wmax[tid] = 1.0f;
  __syncthreads();

  float Cln = 0.0f;  // accumulated log-scale (natural log), uniform across threads
  for (int t = 1; t < L; ++t) {
    // ---- phase A: read-only compute on av/ev ----
    float U = wmax[0];
#pragma unroll
    for (int w = 1; w < 8; ++w) U = fmaxf(U, wmax[w]);
    int ex = (__float_as_int(U) >> 23) & 255;          // exponent of current ev max
    float r = __int_as_float((254 - ex) << 23);        // exact 2^-(ex-127)
    Cln += (float)(ex - 127) * 0.6931471805599453f;

    if (tid < KK) emit_s[tid] = logits[(b * TT + t) * KK + tid];

    float mv = -3.4e38f; int ai = 0; float S = 0.0f;
    const float4* av4 = (const float4*)(av + 36 * sub);
    const float4* ev4 = (const float4*)(ev + 36 * sub);
#pragma unroll
    for (int q = 0; q < 8; ++q) {
      float4 a4 = av4[q];
      float4 e4 = ev4[q];
      int ib = i0 + q * 4;
      float s0 = a4.x + tv[q*4+0]; if (s0 > mv) { mv = s0; ai = ib;   } S = fmaf(e4.x, tw[q*4+0], S);
      float s1 = a4.y + tv[q*4+1]; if (s1 > mv) { mv = s1; ai = ib+1; } S = fmaf(e4.y, tw[q*4+1], S);
      float s2 = a4.z + tv[q*4+2]; if (s2 > mv) { mv = s2; ai = ib+2; } S = fmaf(e4.z, tw[q*4+2], S);
      float s3 = a4.w + tv[q*4+3]; if (s3 > mv) { mv = s3; ai = ib+3; } S = fmaf(e4.w, tw[q*4+3], S);
    }
    // combine the 4 i-subranges (lanes differing in bits 0..1); first-index tie-break
#pragma unroll
    for (int m = 1; m <= 2; m <<= 1) {
      float om = __shfl_xor(mv, m);
      int   oi = __shfl_xor(ai, m);
      float oS = __shfl_xor(S, m);
      if (om > mv || (om == mv && oi < ai)) { mv = om; ai = oi; }
      S += oS;
    }
    __syncthreads();   // all reads of av/ev done

    // ---- phase B: write new state ----
    float em = emit_s[j];
    float u = S * __expf(em);
    float evn = u * r;
    if (sub == 0) {
      av[AIDX(j)] = mv + em;                          // bitwise matches reference chain
      ev[AIDX(j)] = evn;
      bp[(b * TT + t) * KK + j] = (unsigned char)ai;
    }
    // per-wave max of evn (each wave covers 16 distinct j, 4x replicated)
    float wm = evn;
    wm = fmaxf(wm, __shfl_xor(wm, 4));
    wm = fmaxf(wm, __shfl_xor(wm, 8));
    wm = fmaxf(wm, __shfl_xor(wm, 16));
    wm = fmaxf(wm, __shfl_xor(wm, 32));
    if ((tid & 63) == 0) wmax[tid >> 6] = wm;
    __syncthreads();   // writes visible for next phase A
  }

  // ---- final argmax (viterbi 'last'), ev sum (log_norm), sequence score ----
  {
    float v = (tid < KK) ? av[AIDX(tid)] : -3.4e38f;
    int idx = (tid < KK) ? tid : KK;
#pragma unroll
    for (int m = 1; m < 64; m <<= 1) {
      float ov = __shfl_xor(v, m);
      int oi = __shfl_xor(idx, m);
      if (ov > v || (ov == v && oi < idx)) { v = ov; idx = oi; }
    }
    if ((tid & 63) == 0) { rv[tid >> 6] = v; ri[tid >> 6] = idx; }
  }
  {
    float s = (tid < KK) ? ev[AIDX(tid)] : 0.0f;
#pragma unroll
    for (int m = 1; m < 64; m <<= 1) s += __shfl_xor(s, m);
    if ((tid & 63) == 0) rs[tid >> 6] = s;
  }
  float sc = 0.0f;
  for (int tt2 = tid; tt2 < L; tt2 += 512) {
    int lab = labels[b * TT + tt2];
    sc += logits[(b * TT + tt2) * KK + lab];
    if (tt2 >= 1) sc += trans[labels[b * TT + tt2 - 1] * KK + lab];
  }
#pragma unroll
  for (int m = 1; m < 64; m <<= 1) sc += __shfl_xor(sc, m);
  if ((tid & 63) == 0) rsc[tid >> 6] = sc;
  __syncthreads();

  if (tid == 0) {
    float bv = rv[0]; int bi = ri[0];
    float es = rs[0]; float scf = rsc[0];
#pragma unroll
    for (int w = 1; w < 8; ++w) {
      if (rv[w] > bv || (rv[w] == bv && ri[w] < bi)) { bv = rv[w]; bi = ri[w]; }
      es += rs[w]; scf += rsc[w];
    }
    last_s = bi;
    float log_norm = Cln + logf(es);
    negll[b] = log_norm - scf;
  }
  __syncthreads();

  const int last = last_s;
  if (tid >= L - 1) tags[tid] = (unsigned char)last;   // positions L-1..T-1 = last
  __syncthreads();

  // ---- backtrace by wave 0: chunked row prefetch + shfl extraction ----
  if (tid < 64) {
    const int lane = tid;
    int tag = last;
    int t = L - 1;
    while (t >= 1) {
      const int nch = (t < 8) ? t : 8;
      unsigned short rows[8];
#pragma unroll
      for (int c = 0; c < 8; ++c) {
        if (c < nch)
          rows[c] = ((const unsigned short*)(bp + (b * TT + (t - c)) * KK))[lane];
      }
#pragma unroll
      for (int c = 0; c < 8; ++c) {
        if (c < nch) {
          int vrow = __shfl((int)rows[c], tag >> 1);
          tag = (vrow >> ((tag & 1) * 8)) & 255;
          if (lane == 0) tags[t - c - 1] = (unsigned char)tag;
        }
      }
      t -= nch;
    }
  }
  __syncthreads();

  pred_out[b * TT + tid] = (float)tags[tid];
}

__global__ void crf_loss_reduce(const float* __restrict__ negll, float* __restrict__ out) {
  int tid = threadIdx.x;
  float v = negll[tid];
#pragma unroll
  for (int m = 1; m < 64; m <<= 1) v += __shfl_xor(v, m);
  __shared__ float p[4];
  if ((tid & 63) == 0) p[tid >> 6] = v;
  __syncthreads();
  if (tid == 0) out[0] = p[0] + p[1] + p[2] + p[3];
}

extern "C" void kernel_launch(void* const* d_in, const int* in_sizes, int n_in,
                              void* d_out, int out_size, void* d_ws, size_t ws_size,
                              hipStream_t stream) {
  const float* logits   = (const float*)d_in[0];
  const int*   labels   = (const int*)d_in[1];
  const int*   seq_lens = (const int*)d_in[2];
  const float* trans    = (const float*)d_in[3];
  float* out = (float*)d_out;

  float* negll = (float*)d_ws;                          // 256 floats
  unsigned char* bp = (unsigned char*)d_ws + 1024;      // B*T*K bytes = 16.8 MB

  crf_forward<<<BB, 512, 0, stream>>>(logits, labels, seq_lens, trans,
                                      out + 1, negll, bp);
  crf_loss_reduce<<<1, 256, 0, stream>>>(negll, out);
}